// Round 4
// baseline (407.504 us; speedup 1.0000x reference)
//
#include <hip/hip_runtime.h>
#include <hip/hip_bf16.h>

// ---- problem constants ----
#define L_IN     220500
#define PADK     1024
#define LP       222548            // L_IN + 2048 (reflect-padded length)
#define LPP      222560            // LP rounded to mult of 16 elems (16B-aligned rows, /8 exact)
#define BATCH    32
#define NFFT     2048
#define HOPSZ    512
#define T_FR     431               // (LP - NFFT)/HOP + 1
#define F_BINS   1025
#define M_TOT    (BATCH * T_FR)    // 13792 (frames)
#define N_TOT    (2 * F_BINS)      // 2050  (interleaved n' = 2k + c)
#define K_TOT    NFFT              // 2048

#define XVEC     (LPP / 8)         // 27820 8-elem chunks per padded row
#define NXWORK   (BATCH * XVEC)    // 890240
#define NWWORK   (N_TOT * K_TOT / 8) // 524800

typedef short  short8  __attribute__((ext_vector_type(8)));
typedef float  floatx4 __attribute__((ext_vector_type(4)));

__device__ __forceinline__ void glds16(const void* g, void* l) {
    __builtin_amdgcn_global_load_lds(
        (const __attribute__((address_space(1))) void*)g,
        (__attribute__((address_space(3))) void*)l, 16, 0, 0);
}

__device__ __forceinline__ unsigned short bf16bits(float f) {
    __hip_bfloat16 h = __float2bfloat16(f);
    return *(unsigned short*)&h;
}

// ---- pass 1 (fused): reflect-pad+convert x, and interleave+convert w ----
__global__ void k_prep(const float* __restrict__ x,
                       const float* __restrict__ wcos, const float* __restrict__ wsin,
                       __hip_bfloat16* __restrict__ xp, __hip_bfloat16* __restrict__ wb) {
    int idx = blockIdx.x * 256 + threadIdx.x;
    if (idx < NXWORK) {
        int b  = idx / XVEC;
        int i0 = (idx - b * XVEC) * 8;
        short8 s;
        if (i0 >= PADK && i0 + 8 <= PADK + L_IN) {          // bulk: vectorized
            const float* src = x + (size_t)b * L_IN + (i0 - PADK);
            float4 f0 = *(const float4*)src;
            float4 f1 = *(const float4*)(src + 4);
            s[0] = bf16bits(f0.x); s[1] = bf16bits(f0.y);
            s[2] = bf16bits(f0.z); s[3] = bf16bits(f0.w);
            s[4] = bf16bits(f1.x); s[5] = bf16bits(f1.y);
            s[6] = bf16bits(f1.z); s[7] = bf16bits(f1.w);
        } else {                                            // edges: reflect
            for (int e = 0; e < 8; ++e) {
                int j = i0 + e - PADK;
                if (j < 0) j = -j;
                if (j >= L_IN) j = 2 * L_IN - 2 - j;
                s[e] = bf16bits(x[(size_t)b * L_IN + j]);
            }
        }
        *(short8*)(xp + (size_t)b * LPP + i0) = s;
    } else if (idx < NXWORK + NWWORK) {
        int widx = idx - NXWORK;
        int np = widx >> 8;                 // 256 chunks per 2048-row
        int k0 = (widx & 255) * 8;
        const float* src = ((np & 1) ? wsin : wcos) + (size_t)(np >> 1) * K_TOT + k0;
        float4 f0 = *(const float4*)src;
        float4 f1 = *(const float4*)(src + 4);
        short8 s;
        s[0] = bf16bits(f0.x); s[1] = bf16bits(f0.y);
        s[2] = bf16bits(f0.z); s[3] = bf16bits(f0.w);
        s[4] = bf16bits(f1.x); s[5] = bf16bits(f1.y);
        s[6] = bf16bits(f1.z); s[7] = bf16bits(f1.w);
        *(short8*)(wb + (size_t)np * K_TOT + k0) = s;
    }
}

// ---- pass 2: bf16 MFMA GEMM (C^T). B via LDS (XOR-swizzled, conflict-free);
//      A fragments loaded DIRECTLY from global (L1-resident, off the LDS pipe). ----
__global__ __launch_bounds__(256, 2) void k_gemm(
    const __hip_bfloat16* __restrict__ xp,
    const __hip_bfloat16* __restrict__ wb,
    float* __restrict__ out) {

    __shared__ short Bs[128 * 64];   // weights [row=n'][16B-chunk c] = global[row][c ^ (row&7)]

    const int tid  = threadIdx.x;
    const int wave = tid >> 6;
    const int lane = tid & 63;
    const int quad = lane >> 4;
    const int waveM = wave >> 1;     // 2x2 wave grid, each wave 64(m) x 64(n')
    const int waveN = wave & 1;
    const int bm = blockIdx.x;       // 108 M-tiles
    const int bn = blockIdx.y;       // 17  N-tiles

    // B staging row bases (8 rows per issue, 4 issues per wave)
    long brow[4];
    for (int q = 0; q < 4; ++q) {
        int row = wave * 32 + q * 8 + (lane >> 3);
        int n = bn * 128 + row; if (n > N_TOT - 1) n = N_TOT - 1;
        brow[q] = (long)n * K_TOT;
    }
    const int colo = (((lane & 7) ^ (lane >> 3)) * 8);  // swizzled source chunk

    // A fragment per-lane global bases (m = bm*128 + waveM*64 + j*16 + (lane&15))
    long abase[4];
    for (int j = 0; j < 4; ++j) {
        int m = bm * 128 + waveM * 64 + j * 16 + (lane & 15);
        if (m > M_TOT - 1) m = M_TOT - 1;          // clamp; masked at store
        int b = m / T_FR, t = m - b * T_FR;
        abase[j] = (long)b * LPP + (long)t * HOPSZ;
    }

    floatx4 acc[4][4] = {};           // acc[i = n'-block][j = m-block]

    for (int k0 = 0; k0 < K_TOT; k0 += 64) {
        for (int q = 0; q < 4; ++q)
            glds16(wb + brow[q] + k0 + colo, (char*)Bs + (wave * 32 + q * 8) * 128);
        __syncthreads();   // drains vmcnt(0) before s_barrier

        for (int kk = 0; kk < 2; ++kk) {
            const int gchunk = kk * 4 + quad;          // global 16B-chunk index
            short8 wf[4], xf[4];
            for (int i = 0; i < 4; ++i) {
                int R = waveN * 64 + i * 16 + (lane & 15);
                wf[i] = *(const short8*)&Bs[R * 64 + ((gchunk ^ (R & 7)) << 3)];
            }
            for (int j = 0; j < 4; ++j)
                xf[j] = *(const short8*)(xp + abase[j] + k0 + kk * 32 + quad * 8);
            for (int i = 0; i < 4; ++i)
                for (int j = 0; j < 4; ++j)
                    // C^T: D rows = n' (first operand), D cols = m (second operand)
                    acc[i][j] = __builtin_amdgcn_mfma_f32_16x16x32_bf16(wf[i], xf[j], acc[i][j], 0, 0, 0);
        }
        __syncthreads();
    }

    // epilogue: lane&15 = m (consecutive t), regs = consecutive n' = (k, re/im) pairs
    // out2[(b*1025 + k)*431 + t] = {real, -imag}  -> 8B/lane, 128B contiguous per quad
    float2* __restrict__ out2 = (float2*)out;
    const int mcol = bm * 128 + waveM * 64 + (lane & 15);
    for (int j = 0; j < 4; ++j) {
        int m = mcol + j * 16;
        if (m >= M_TOT) continue;
        int b = m / T_FR, t = m - b * T_FR;
        long tbase = (long)b * F_BINS * T_FR + t;
        for (int i = 0; i < 4; ++i) {
            int nbase = bn * 128 + waveN * 64 + i * 16 + quad * 4;
            for (int p = 0; p < 2; ++p) {
                int np = nbase + 2 * p;
                if (np >= N_TOT) continue;
                int k = np >> 1;
                float2 v;
                v.x =  acc[i][j][2 * p];        // c=0: wcos conv = real
                v.y = -acc[i][j][2 * p + 1];    // c=1: wsin conv, negated
                out2[tbase + (long)k * T_FR] = v;
            }
        }
    }
}

extern "C" void kernel_launch(void* const* d_in, const int* in_sizes, int n_in,
                              void* d_out, int out_size, void* d_ws, size_t ws_size,
                              hipStream_t stream) {
    const float* x    = (const float*)d_in[0];
    const float* wcos = (const float*)d_in[1];
    const float* wsin = (const float*)d_in[2];
    float* out = (float*)d_out;

    // ws layout: xp_bf16 [32][LPP] then w_bf16 [2050][2048]  (~22.6 MB total)
    __hip_bfloat16* xp = (__hip_bfloat16*)d_ws;
    __hip_bfloat16* wb = (__hip_bfloat16*)((char*)d_ws + (size_t)BATCH * LPP * sizeof(__hip_bfloat16));

    const int prep_items = NXWORK + NWWORK;
    k_prep<<<(prep_items + 255) / 256, 256, 0, stream>>>(x, wcos, wsin, xp, wb);

    const int mt = (M_TOT + 127) / 128;   // 108
    const int nt = (N_TOT + 127) / 128;   // 17
    k_gemm<<<dim3(mt, nt), 256, 0, stream>>>(xp, wb, out);
}